// Round 1
// 3538.314 us; speedup vs baseline: 1.0659x; 1.0659x over previous
//
#include <hip/hip_runtime.h>

#define BB 512
#define TT 256
#define FDIM 128
#define HDIM 512
#define FFD 1024
#define OUTD 64
#define PADV -999.0f
#define NBLK 256
#define NTHR 256

typedef __bf16 bf16_t;
typedef bf16_t bf16x8 __attribute__((ext_vector_type(8)));
typedef float f32x4 __attribute__((ext_vector_type(4)));
typedef unsigned long long u64;

// Fragment-major LDS slabs: each MFMA B-fragment (16 cols x 32 K) stored as
// 64 lanes x 16B contiguous -> ds_read_b128 at lane*16 (linear, conflict-
// free ~12cy). R10's col-pitch layout put all 64 lanes in 8 of 32 banks
// (8-way conflict, SQ_LDS_BANK_CONFLICT 6.15e8).
union LdsU {
  struct {                        // A-role (GRU gates), 128 blocks
    bf16_t rzf[80 * 64 * 8];      // [j<4][ks<20: 0..3 x-part, 4..19 h-part]
    bf16_t nhf[32 * 64 * 8];      // [j2<2][ks<16] h_n (Whh rows 1024+)
    bf16_t nif[8 * 64 * 8];       // [j2<2][ks<4]  i_n (Wih rows 1024+)
    float  ex[4][64][33];         // gate exchange [r,z,nh,ni][row][col]
  } a;
  struct {                        // B-role (FF1) + C-addon (FF2), 128 blocks
    bf16_t w1f[64 * 64 * 8];      // [j<4][ks<16]
    bf16_t w2f[32 * 64 * 8];      // [ks<32]
    bf16_t st[64 * 72];           // FF1 output restage
  } b;
};

__device__ __forceinline__ f32x4 mfma16(bf16x8 a, bf16x8 b, f32x4 c) {
  return __builtin_amdgcn_mfma_f32_16x16x32_bf16(a, b, c, 0, 0, 0);
}
__device__ __forceinline__ float sigm(float x) { return 1.f / (1.f + __expf(-x)); }
__device__ __forceinline__ float tanh_f(float x) { return 2.f / (1.f + __expf(-2.f * x)) - 1.f; }

// Monotonic-counter wait, agent-scope relaxed (counters live at L3 coherence
// point; producers increment only after __syncthreads drained their stores).
__device__ __forceinline__ void wait_ge(unsigned* p, unsigned v) {
  while (__hip_atomic_load(p, __ATOMIC_RELAXED, __HIP_MEMORY_SCOPE_AGENT) < v)
    __builtin_amdgcn_s_sleep(1);
}

// LESSONS (stub-failure = silent compile fail -> harness fallback):
//  1. __hip_atomic_* pointer args must be NON-CONST, used inline.
//  2. NO prefetch arrays >= 64 VGPRs feeding unrolled MFMA loops.
//
// R11: kill the grid-wide lockstep barrier (≈11 us/iter of the 14.6 us/iter
// cadence). Replace with per-batch-group (intra-XCD, 16-block) monotonic
// counters:
//   barA[g]  A-sibling barrier per step + "ff[t]/h[t] visible" release to B
//   barB[g]  B completion: "hd[t] visible" to C + ff ping-pong back-pressure
//   barC[g]  C completion: hd ping-pong back-pressure to B
// Slack-1 pipeline; only the 16 A blocks of a group sync per timestep.
// h_{-1} zeroing is per-A-block own shard + one zero-phase arrival (no grid
// rendezvous anywhere). Data plane unchanged (proven: agent-relaxed stores
// drain at __syncthreads, then flag increment).

__global__ __launch_bounds__(NTHR) void gru_net_kernel(
    const float* __restrict__ x, const int* __restrict__ seq,
    const float* __restrict__ Wih, const float* __restrict__ Whh,
    const float* __restrict__ bih, const float* __restrict__ bhh,
    const float* __restrict__ W1, const float* __restrict__ b1,
    const float* __restrict__ W2, const float* __restrict__ b2,
    float* __restrict__ out,
    bf16_t* __restrict__ hb, bf16_t* __restrict__ ff, bf16_t* __restrict__ hd,
    unsigned* __restrict__ bar) {
  __shared__ LdsU L;
  __shared__ float biasA[4][32];
  __shared__ float b1s[64];
  __shared__ float b2s[16];
  __shared__ int   seqA[64];
  __shared__ int   seqC[64];

  const int blk = blockIdx.x, tid = threadIdx.x;
  const int wv = tid >> 6, lane = tid & 63;
  const int q = lane >> 4, col16 = lane & 15, q8 = q * 8;
  const bool isA = blk < 128;

  // XCD-locality remap: batch-group = blk%8 (round-robin blk->XCD) so each
  // group's A producers and B/C consumers share one XCD L2.
  const int grp = isA ? (blk & 7) : ((blk - 128) & 7);
  unsigned* barA = bar + grp * 32;           // 128B-isolated lines
  unsigned* barB = bar + (8 + grp) * 32;
  unsigned* barC = bar + (16 + grp) * 32;

  int b0 = 0, c0 = 0, f0 = 0, b0c = 0, o0 = 0;
  bool hasC = false;
  if (isA) {
    b0 = (blk & 7) * 64;           // batch row group (8)
    c0 = (blk >> 3) * 32;          // h-col group (16)
    // rzf: frag fi=j*20+ks; lane(q,c) elem e = W[grow(j*16+c)][k], where
    // ks<4 -> Wih k=ks*32+q*8+e ; ks>=4 -> Whh k=(ks-4)*32+q*8+e
    for (int i = tid; i < 80 * 64; i += NTHR) {
      const int ln = i & 63, fi = i >> 6;
      const int j = fi / 20, ks = fi - j * 20;
      const int cc = ln & 15, qq = ln >> 4;
      const int colj = j * 16 + cc;
      const int grow = (colj < 32) ? (c0 + colj) : (512 + c0 + (colj - 32));
      bf16_t* dst = &L.a.rzf[(size_t)i * 8];
      if (ks < 4) {
        const float* src = Wih + (size_t)grow * FDIM + ks * 32 + qq * 8;
        for (int e = 0; e < 8; ++e) dst[e] = (bf16_t)src[e];
      } else {
        const float* src = Whh + (size_t)grow * HDIM + (ks - 4) * 32 + qq * 8;
        for (int e = 0; e < 8; ++e) dst[e] = (bf16_t)src[e];
      }
    }
    for (int i = tid; i < 32 * 64; i += NTHR) {   // nhf: fi=j2*16+ks
      const int ln = i & 63, fi = i >> 6;
      const int j2 = fi >> 4, ks = fi & 15;
      const int cc = ln & 15, qq = ln >> 4;
      const int grow = 1024 + c0 + j2 * 16 + cc;
      const float* src = Whh + (size_t)grow * HDIM + ks * 32 + qq * 8;
      bf16_t* dst = &L.a.nhf[(size_t)i * 8];
      for (int e = 0; e < 8; ++e) dst[e] = (bf16_t)src[e];
    }
    for (int i = tid; i < 8 * 64; i += NTHR) {    // nif: fi=j2*4+ks
      const int ln = i & 63, fi = i >> 6;
      const int j2 = fi >> 2, ks = fi & 3;
      const int cc = ln & 15, qq = ln >> 4;
      const int grow = 1024 + c0 + j2 * 16 + cc;
      const float* src = Wih + (size_t)grow * FDIM + ks * 32 + qq * 8;
      bf16_t* dst = &L.a.nif[(size_t)i * 8];
      for (int e = 0; e < 8; ++e) dst[e] = (bf16_t)src[e];
    }
    if (tid < 32) {
      biasA[0][tid] = bih[c0 + tid] + bhh[c0 + tid];
      biasA[1][tid] = bih[512 + c0 + tid] + bhh[512 + c0 + tid];
      biasA[2][tid] = bih[1024 + c0 + tid];   // i_n bias
      biasA[3][tid] = bhh[1024 + c0 + tid];   // h_n bias
    }
    if (tid < 64) seqA[tid] = seq[b0 + tid];

    // zero OWN shard of h_{-1} (slot 1): 64 rows x 32 cols, 8B stores
    for (int i = tid; i < 512; i += NTHR) {
      const int r = i >> 3, cq = (i & 7) * 4;
      __hip_atomic_store((u64*)(hb + (size_t)BB * HDIM + (size_t)(b0 + r) * HDIM + c0 + cq),
                         0ull, __ATOMIC_RELAXED, __HIP_MEMORY_SCOPE_AGENT);
    }
    __syncthreads();                         // drain zero stores + LDS staging
    if (tid == 0) atomicAdd(barA, 1u);       // zero-phase arrival (barA: +16)

    // ---- A loop: one GRU timestep per iteration, group-local sync ----
    for (int t = 0; t < TT; ++t) {
      if (tid == 0) {
        if (t >= 2) wait_ge(barB, 16u * (unsigned)(t - 1));  // ff[t-2] consumed
        wait_ge(barA, 16u * (unsigned)(t + 1));              // siblings done t-1
      }
      __syncthreads();

      bf16_t* hr = hb + (size_t)((t + 1) & 1) * BB * HDIM;
      bf16_t* hw = hb + (size_t)(t & 1) * BB * HDIM;
      bf16_t* fw = ff + (size_t)(t & 1) * BB * HDIM;
      const int rA = b0 + wv * 16 + col16;
      const float* paxf = x + ((size_t)rA * TT + t) * FDIM;
      bf16_t* pah = hr + (size_t)rA * HDIM;
      const f32x4 zz = {0.f, 0.f, 0.f, 0.f};
      f32x4 acc[4] = {zz, zz, zz, zz};
      f32x4 accn[2] = {zz, zz};
      f32x4 acci[2] = {zz, zz};
      // x part: ks 0..3 feeds rzf (x-frags) and nif
      #pragma unroll
      for (int ks = 0; ks < 4; ++ks) {
        const int ko = ks * 32 + q8;
        const float4 u0 = *(const float4*)(paxf + ko);
        const float4 u1 = *(const float4*)(paxf + ko + 4);
        bf16x8 av;
        av[0]=(bf16_t)u0.x; av[1]=(bf16_t)u0.y; av[2]=(bf16_t)u0.z; av[3]=(bf16_t)u0.w;
        av[4]=(bf16_t)u1.x; av[5]=(bf16_t)u1.y; av[6]=(bf16_t)u1.z; av[7]=(bf16_t)u1.w;
        #pragma unroll
        for (int j = 0; j < 4; ++j) {
          const bf16x8 bv = *(const bf16x8*)&L.a.rzf[(size_t)((j * 20 + ks) * 64 + lane) * 8];
          acc[j] = mfma16(av, bv, acc[j]);
        }
        #pragma unroll
        for (int j = 0; j < 2; ++j) {
          const bf16x8 bv = *(const bf16x8*)&L.a.nif[(size_t)((j * 4 + ks) * 64 + lane) * 8];
          acci[j] = mfma16(av, bv, acci[j]);
        }
      }
      // h part: ks 0..15 feeds rzf (h-frags) and nhf; coherent 8B loads
      #pragma unroll 4
      for (int ks = 0; ks < 16; ++ks) {
        const int ko = ks * 32 + q8;
        u64 hq[2];
        hq[0] = __hip_atomic_load((u64*)(pah + ko),     __ATOMIC_RELAXED, __HIP_MEMORY_SCOPE_AGENT);
        hq[1] = __hip_atomic_load((u64*)(pah + ko) + 1, __ATOMIC_RELAXED, __HIP_MEMORY_SCOPE_AGENT);
        const bf16x8 av = *(const bf16x8*)hq;
        #pragma unroll
        for (int j = 0; j < 4; ++j) {
          const bf16x8 bv = *(const bf16x8*)&L.a.rzf[(size_t)((j * 20 + 4 + ks) * 64 + lane) * 8];
          acc[j] = mfma16(av, bv, acc[j]);
        }
        #pragma unroll
        for (int j = 0; j < 2; ++j) {
          const bf16x8 bv = *(const bf16x8*)&L.a.nhf[(size_t)((j * 16 + ks) * 64 + lane) * 8];
          accn[j] = mfma16(av, bv, accn[j]);
        }
      }
      // dump gate sums to LDS exchange (C/D: col=lane&15, row=q*4+reg)
      #pragma unroll
      for (int j = 0; j < 4; ++j) {
        const int sl = j >> 1, cb = (j & 1) * 16 + col16;
        #pragma unroll
        for (int rg = 0; rg < 4; ++rg)
          L.a.ex[sl][wv * 16 + q * 4 + rg][cb] = acc[j][rg];
      }
      #pragma unroll
      for (int j = 0; j < 2; ++j) {
        const int cb = j * 16 + col16;
        #pragma unroll
        for (int rg = 0; rg < 4; ++rg) {
          L.a.ex[2][wv * 16 + q * 4 + rg][cb] = accn[j][rg];
          L.a.ex[3][wv * 16 + q * 4 + rg][cb] = acci[j][rg];
        }
      }
      __syncthreads();
      // elementwise GRU update, 4 cols/thread, 8B coherent I/O
      for (int e = tid; e < 512; e += NTHR) {
        const int row = e >> 3, cq = (e & 7) << 2;
        const int bidx = b0 + row;
        u64 hp8 = __hip_atomic_load((u64*)(hr + (size_t)bidx * HDIM + c0 + cq),
                                    __ATOMIC_RELAXED, __HIP_MEMORY_SCOPE_AGENT);
        const bf16_t* hp4 = (const bf16_t*)&hp8;
        bf16_t hw4[4], fw4[4];
        const bool v = (t < seqA[row]);
        #pragma unroll
        for (int j = 0; j < 4; ++j) {
          const int c = cq + j;
          const float gr  = L.a.ex[0][row][c] + biasA[0][c];
          const float gz  = L.a.ex[1][row][c] + biasA[1][c];
          const float gnh = L.a.ex[2][row][c] + biasA[3][c];
          const float gni = L.a.ex[3][row][c] + biasA[2][c];
          const float r = sigm(gr), zg = sigm(gz);
          const float n = tanh_f(gni + r * gnh);
          const float hp = (float)hp4[j];
          const float hnew = (1.f - zg) * n + zg * hp;
          hw4[j] = (bf16_t)(v ? hnew : hp);
          fw4[j] = (bf16_t)(v ? hnew : 0.f);
        }
        __hip_atomic_store((u64*)(hw + (size_t)bidx * HDIM + c0 + cq), *(u64*)hw4,
                           __ATOMIC_RELAXED, __HIP_MEMORY_SCOPE_AGENT);
        __hip_atomic_store((u64*)(fw + (size_t)bidx * HDIM + c0 + cq), *(u64*)fw4,
                           __ATOMIC_RELAXED, __HIP_MEMORY_SCOPE_AGENT);
      }
      __syncthreads();                       // drain h/ff stores
      if (tid == 0) atomicAdd(barA, 1u);     // release: h[t], ff[t] visible
    }
  } else {
    const int cidx = blk - 128;
    b0 = (cidx & 7) * 64;          // batch group (same XCD residue as A)
    f0 = (cidx >> 3) * 64;         // FF col group (16)
    for (int i = tid; i < 64 * 64; i += NTHR) {   // w1f: fi=j*16+ks
      const int ln = i & 63, fi = i >> 6;
      const int j = fi >> 4, ks = fi & 15;
      const int cc = ln & 15, qq = ln >> 4;
      const int fcol = f0 + j * 16 + cc;
      const int kb = ks * 32 + qq * 8;
      bf16_t* dst = &L.b.w1f[(size_t)i * 8];
      for (int e = 0; e < 8; ++e) dst[e] = (bf16_t)W1[(size_t)(kb + e) * FFD + fcol];
    }
    if (tid < 64) b1s[tid] = b1[f0 + tid];
    hasC = (cidx < 32);
    if (hasC) {
      b0c = (cidx & 7) * 64;       // batch group (same XCD residue)
      o0 = (cidx >> 3) * 16;       // out col group (4)
      for (int i = tid; i < 32 * 64; i += NTHR) { // w2f: fi=ks
        const int ln = i & 63, ks = i >> 6;
        const int cc = ln & 15, qq = ln >> 4;
        const int kb = ks * 32 + qq * 8;
        bf16_t* dst = &L.b.w2f[(size_t)i * 8];
        for (int e = 0; e < 8; ++e) dst[e] = (bf16_t)W2[(kb + e) * OUTD + o0 + cc];
      }
      if (tid < 16) b2s[tid] = b2[o0 + tid];
      if (tid < 64) seqC[tid] = seq[b0c + tid];
    }
    __syncthreads();               // LDS staging visible block-wide

    // ---- B/C loop: iter u does FF1(t=u) then FF2(t=u-1), own cadence ----
    for (int u = 0; u <= TT; ++u) {
      if (tid == 0) {
        if (u < TT) {
          if (u >= 2) wait_ge(barC, 4u * (unsigned)(u - 1));   // hd[u-2] consumed
          wait_ge(barA, 16u * (unsigned)(u + 2));              // ff[u] visible
        }
        if (hasC && u >= 1) wait_ge(barB, 16u * (unsigned)u);  // hd[u-1] visible
      }
      __syncthreads();

      if (u < TT) {                        // FF1 for t = u
        const int t = u;
        bf16_t* fr = ff + (size_t)(t & 1) * BB * HDIM;
        bf16_t* hwid = hd + (size_t)(t & 1) * BB * FFD;
        const int rB = b0 + wv * 16 + col16;
        bf16_t* pa = fr + (size_t)rB * HDIM;
        const f32x4 zz = {0.f, 0.f, 0.f, 0.f};
        f32x4 acc[4] = {zz, zz, zz, zz};
        #pragma unroll 4
        for (int ks = 0; ks < 16; ++ks) {
          const int ko = ks * 32 + q8;
          u64 fq[2];
          fq[0] = __hip_atomic_load((u64*)(pa + ko),     __ATOMIC_RELAXED, __HIP_MEMORY_SCOPE_AGENT);
          fq[1] = __hip_atomic_load((u64*)(pa + ko) + 1, __ATOMIC_RELAXED, __HIP_MEMORY_SCOPE_AGENT);
          const bf16x8 av = *(const bf16x8*)fq;
          #pragma unroll
          for (int j = 0; j < 4; ++j) {
            const bf16x8 bv = *(const bf16x8*)&L.b.w1f[(size_t)((j * 16 + ks) * 64 + lane) * 8];
            acc[j] = mfma16(av, bv, acc[j]);
          }
        }
        // relu + bias -> LDS restage -> contiguous 8B coherent stores
        #pragma unroll
        for (int j = 0; j < 4; ++j) {
          const int fc = j * 16 + col16;
          #pragma unroll
          for (int rg = 0; rg < 4; ++rg)
            L.b.st[(wv * 16 + q * 4 + rg) * 72 + fc] =
                (bf16_t)fmaxf(acc[j][rg] + b1s[fc], 0.f);
        }
        __syncthreads();
        for (int w = tid; w < 1024; w += NTHR) {
          const int r = w >> 4, cq = (w & 15) * 4;
          const u64 pk = *(const u64*)&L.b.st[r * 72 + cq];
          __hip_atomic_store((u64*)(hwid + (size_t)(b0 + r) * FFD + f0 + cq), pk,
                             __ATOMIC_RELAXED, __HIP_MEMORY_SCOPE_AGENT);
        }
      }
      if (hasC && u >= 1) {                // FF2 for t = u-1
        const int t = u - 1;
        bf16_t* hr2 = hd + (size_t)(t & 1) * BB * FFD;
        const int rC = b0c + wv * 16 + col16;
        bf16_t* pa = hr2 + (size_t)rC * FFD;
        f32x4 acc = {0.f, 0.f, 0.f, 0.f};
        #pragma unroll 4
        for (int ks = 0; ks < 32; ++ks) {
          const int ko = ks * 32 + q8;
          u64 hq[2];
          hq[0] = __hip_atomic_load((u64*)(pa + ko),     __ATOMIC_RELAXED, __HIP_MEMORY_SCOPE_AGENT);
          hq[1] = __hip_atomic_load((u64*)(pa + ko) + 1, __ATOMIC_RELAXED, __HIP_MEMORY_SCOPE_AGENT);
          const bf16x8 av = *(const bf16x8*)hq;
          const bf16x8 bv = *(const bf16x8*)&L.b.w2f[(size_t)(ks * 64 + lane) * 8];
          acc = mfma16(av, bv, acc);
        }
        #pragma unroll
        for (int rg = 0; rg < 4; ++rg) {
          const int lr = wv * 16 + q * 4 + rg;
          const int rb = b0c + lr;
          const float v = acc[rg] + b2s[col16];
          out[((size_t)rb * TT + t) * OUTD + o0 + col16] = (t < seqC[lr]) ? v : PADV;
        }
      }
      __syncthreads();                     // drain hd stores / FF2 loads done
      if (tid == 0) {
        if (u < TT) atomicAdd(barB, 1u);   // hd[u] visible + ff[u] consumed
        if (hasC && u >= 1) atomicAdd(barC, 1u);  // hd[u-1] consumed
      }
    }
  }
}

extern "C" void kernel_launch(void* const* d_in, const int* in_sizes, int n_in,
                              void* d_out, int out_size, void* d_ws, size_t ws_size,
                              hipStream_t stream) {
  const float* x   = (const float*)d_in[0];
  const int*   seq = (const int*)d_in[1];
  const float* Wih = (const float*)d_in[2];
  const float* Whh = (const float*)d_in[3];
  const float* bih = (const float*)d_in[4];
  const float* bhh = (const float*)d_in[5];
  const float* W1  = (const float*)d_in[6];
  const float* b1  = (const float*)d_in[7];
  const float* W2  = (const float*)d_in[8];
  const float* b2  = (const float*)d_in[9];
  float* out = (float*)d_out;
  char* ws = (char*)d_ws;

  unsigned* bar = (unsigned*)ws;                       // 24 counters, 128B apart
  bf16_t* hb = (bf16_t*)(ws + 4096);                   // h ping-pong  2*B*H
  bf16_t* ff = hb + (size_t)2 * BB * HDIM;             // ffin ping-pong
  bf16_t* hd = ff + (size_t)2 * BB * HDIM;             // hid ping-pong 2*B*FF
  // total scratch ~4.2 MB (same envelope as R5/R7/R10)

  hipMemsetAsync(ws, 0, 4096, stream);
  void* args[] = {&x, &seq, &Wih, &Whh, &bih, &bhh, &W1, &b1, &W2, &b2,
                  &out, &hb, &ff, &hd, &bar};
  hipLaunchCooperativeKernel((void*)gru_net_kernel, dim3(NBLK), dim3(NTHR),
                             args, 0, stream);
}

// Round 5
// 2926.751 us; speedup vs baseline: 1.2886x; 1.2090x over previous
//
#include <hip/hip_runtime.h>

#define BB 512
#define TT 256
#define FDIM 128
#define HDIM 512
#define FFD 1024
#define OUTD 64
#define PADV -999.0f
#define NBLK 256
#define NTHR 256
#define PGRP (4 * 64 * 16)        // pscr floats per (group): 4 ocol x 64 rows x 16 cols
#define PSLOT (8 * PGRP)          // pscr floats per ping-pong slot (8 groups)

typedef __bf16 bf16_t;
typedef bf16_t bf16x8 __attribute__((ext_vector_type(8)));
typedef float f32x4 __attribute__((ext_vector_type(4)));
typedef unsigned long long u64;

// Fragment-major LDS slabs: each MFMA B-fragment (16 cols x 32 K) stored as
// 64 lanes x 16B contiguous -> ds_read_b128 at lane*16 (linear, conflict-
// free ~12cy).
union LdsU {
  struct {                        // A-role (GRU gates), 128 blocks
    bf16_t rzf[80 * 64 * 8];      // [j<4][ks<20: 0..3 x-part, 4..19 h-part]
    bf16_t nhf[32 * 64 * 8];      // [j2<2][ks<16] h_n (Whh rows 1024+)
    bf16_t nif[8 * 64 * 8];       // [j2<2][ks<4]  i_n (Wih rows 1024+)
    float  ex[4][64][33];         // gate exchange [r,z,nh,ni][row][col]
  } a;
  struct {                        // B-role (FF1 + FF2-chunk), 128 blocks
    bf16_t w1f[64 * 64 * 8];      // [j<4][ks<16]
    bf16_t w2f[8 * 64 * 8];       // [ks<8] own K-quarter of W2
    bf16_t st[64 * 72];           // FF1 output restage
  } b;
};

__device__ __forceinline__ f32x4 mfma16(bf16x8 a, bf16x8 b, f32x4 c) {
  return __builtin_amdgcn_mfma_f32_16x16x32_bf16(a, b, c, 0, 0, 0);
}
__device__ __forceinline__ float sigm(float x) { return 1.f / (1.f + __expf(-x)); }
__device__ __forceinline__ float tanh_f(float x) { return 2.f / (1.f + __expf(-2.f * x)) - 1.f; }

// Monotonic-counter wait, agent-scope relaxed.
__device__ __forceinline__ void wait_ge(unsigned* p, unsigned v) {
  while (__hip_atomic_load(p, __ATOMIC_RELAXED, __HIP_MEMORY_SCOPE_AGENT) < v)
    __builtin_amdgcn_s_sleep(1);
}

// LESSONS (stub-failure = silent compile fail -> harness fallback):
//  1. __hip_atomic_* pointer args must be NON-CONST, used inline.
//  2. NO prefetch arrays >= 64 VGPRs feeding unrolled MFMA loops.
//  3. R12: inline-asm `global_load_* sc0 sc1` data loads -> stub fallback.
//  4. R12/R13/R14: EVERY attempt to batch >2 adjacent coherent loads
//     (asm, u64[16] arrays, named u64[2] pairs via macros) -> absmax
//     exactly 1000.0 = ones-stub = silent build failure. Cause unknown.
//     RULE: only the R11-verbatim load idiom (u64 hq[2]; hq[0]=...;
//     hq[1]=...; consume immediately). Optimize via work partition, not ILP.
//
// R15: flatten the 48-trip hasC chain (FF1 16 + FF2 32) by splitting FF2's
// K=1024 into 4 chunks of 256 (8 trips) spread over all 128 B blocks:
// cidx -> (group g=cidx&7, fc=cidx>>3); oc=fc&3 (out-col group), kq=fc>>2
// (K-quarter). Chunks atomicAdd partial sums into pscr[g][oc] (intra-XCD,
// f32). Blocks with fc<4 finalize t-2: coherent read + bias + PADV ->
// out, then re-zero the slot (replay-safe). Worst chain 16+8+2 ~= 26 trips.
//
// Sync: barA[g]: A sibling barrier + "h[t]/ff[t] visible" (unchanged).
// barB[g]: B sibling barrier, incremented once per B iter; barB >= 16u at
// head of iter u transitively gives: hd[u-2] consumed (overwrite-safe),
// hd[u-1] visible, pscr adds for t=u-2 complete, slot (u&1) re-zeroed.
// barC retired.

__global__ __launch_bounds__(NTHR) void gru_net_kernel(
    const float* __restrict__ x, const int* __restrict__ seq,
    const float* __restrict__ Wih, const float* __restrict__ Whh,
    const float* __restrict__ bih, const float* __restrict__ bhh,
    const float* __restrict__ W1, const float* __restrict__ b1,
    const float* __restrict__ W2, const float* __restrict__ b2,
    float* __restrict__ out,
    bf16_t* __restrict__ hb, bf16_t* __restrict__ ff, bf16_t* __restrict__ hd,
    float* __restrict__ psc, unsigned* __restrict__ bar) {
  __shared__ LdsU L;
  __shared__ float biasA[4][32];
  __shared__ float b1s[64];
  __shared__ float b2s[16];
  __shared__ int   seqA[64];
  __shared__ int   seqC[64];

  const int blk = blockIdx.x, tid = threadIdx.x;
  const int wv = tid >> 6, lane = tid & 63;
  const int q = lane >> 4, col16 = lane & 15, q8 = q * 8;
  const bool isA = blk < 128;

  const int grp = isA ? (blk & 7) : ((blk - 128) & 7);
  unsigned* barA = bar + grp * 32;           // 128B-isolated lines
  unsigned* barB = bar + (8 + grp) * 32;

  int b0 = 0, c0 = 0, f0 = 0;
  if (isA) {
    b0 = (blk & 7) * 64;           // batch row group (8)
    c0 = (blk >> 3) * 32;          // h-col group (16)
    // rzf: frag fi=j*20+ks; lane(q,c) elem e = W[grow(j*16+c)][k], where
    // ks<4 -> Wih k=ks*32+q*8+e ; ks>=4 -> Whh k=(ks-4)*32+q*8+e
    for (int i = tid; i < 80 * 64; i += NTHR) {
      const int ln = i & 63, fi = i >> 6;
      const int j = fi / 20, ks = fi - j * 20;
      const int cc = ln & 15, qq = ln >> 4;
      const int colj = j * 16 + cc;
      const int grow = (colj < 32) ? (c0 + colj) : (512 + c0 + (colj - 32));
      bf16_t* dst = &L.a.rzf[(size_t)i * 8];
      if (ks < 4) {
        const float* src = Wih + (size_t)grow * FDIM + ks * 32 + qq * 8;
        for (int e = 0; e < 8; ++e) dst[e] = (bf16_t)src[e];
      } else {
        const float* src = Whh + (size_t)grow * HDIM + (ks - 4) * 32 + qq * 8;
        for (int e = 0; e < 8; ++e) dst[e] = (bf16_t)src[e];
      }
    }
    for (int i = tid; i < 32 * 64; i += NTHR) {   // nhf: fi=j2*16+ks
      const int ln = i & 63, fi = i >> 6;
      const int j2 = fi >> 4, ks = fi & 15;
      const int cc = ln & 15, qq = ln >> 4;
      const int grow = 1024 + c0 + j2 * 16 + cc;
      const float* src = Whh + (size_t)grow * HDIM + ks * 32 + qq * 8;
      bf16_t* dst = &L.a.nhf[(size_t)i * 8];
      for (int e = 0; e < 8; ++e) dst[e] = (bf16_t)src[e];
    }
    for (int i = tid; i < 8 * 64; i += NTHR) {    // nif: fi=j2*4+ks
      const int ln = i & 63, fi = i >> 6;
      const int j2 = fi >> 2, ks = fi & 3;
      const int cc = ln & 15, qq = ln >> 4;
      const int grow = 1024 + c0 + j2 * 16 + cc;
      const float* src = Wih + (size_t)grow * FDIM + ks * 32 + qq * 8;
      bf16_t* dst = &L.a.nif[(size_t)i * 8];
      for (int e = 0; e < 8; ++e) dst[e] = (bf16_t)src[e];
    }
    if (tid < 32) {
      biasA[0][tid] = bih[c0 + tid] + bhh[c0 + tid];
      biasA[1][tid] = bih[512 + c0 + tid] + bhh[512 + c0 + tid];
      biasA[2][tid] = bih[1024 + c0 + tid];   // i_n bias
      biasA[3][tid] = bhh[1024 + c0 + tid];   // h_n bias
    }
    if (tid < 64) seqA[tid] = seq[b0 + tid];

    // zero OWN shard of h_{-1} (slot 1): 64 rows x 32 cols, 8B stores
    for (int i = tid; i < 512; i += NTHR) {
      const int r = i >> 3, cq = (i & 7) * 4;
      __hip_atomic_store((u64*)(hb + (size_t)BB * HDIM + (size_t)(b0 + r) * HDIM + c0 + cq),
                         0ull, __ATOMIC_RELAXED, __HIP_MEMORY_SCOPE_AGENT);
    }
    __syncthreads();                         // drain zero stores + LDS staging
    if (tid == 0) atomicAdd(barA, 1u);       // zero-phase arrival (barA: +16)

    // ---- A loop: one GRU timestep per iteration, group-local sync ----
    for (int t = 0; t < TT; ++t) {
      if (tid == 0) {
        if (t >= 2) wait_ge(barB, 16u * (unsigned)(t - 1));  // ff[t-2] consumed
        wait_ge(barA, 16u * (unsigned)(t + 1));              // siblings done t-1
      }
      __syncthreads();

      bf16_t* hr = hb + (size_t)((t + 1) & 1) * BB * HDIM;
      bf16_t* hw = hb + (size_t)(t & 1) * BB * HDIM;
      bf16_t* fw = ff + (size_t)(t & 1) * BB * HDIM;
      const int rA = b0 + wv * 16 + col16;
      const float* paxf = x + ((size_t)rA * TT + t) * FDIM;
      bf16_t* pah = hr + (size_t)rA * HDIM;
      const f32x4 zz = {0.f, 0.f, 0.f, 0.f};
      f32x4 acc[4] = {zz, zz, zz, zz};
      f32x4 accn[2] = {zz, zz};
      f32x4 acci[2] = {zz, zz};
      // x part: ks 0..3 feeds rzf (x-frags) and nif (plain cached loads)
      #pragma unroll
      for (int ks = 0; ks < 4; ++ks) {
        const int ko = ks * 32 + q8;
        const float4 u0 = *(const float4*)(paxf + ko);
        const float4 u1 = *(const float4*)(paxf + ko + 4);
        bf16x8 av;
        av[0]=(bf16_t)u0.x; av[1]=(bf16_t)u0.y; av[2]=(bf16_t)u0.z; av[3]=(bf16_t)u0.w;
        av[4]=(bf16_t)u1.x; av[5]=(bf16_t)u1.y; av[6]=(bf16_t)u1.z; av[7]=(bf16_t)u1.w;
        #pragma unroll
        for (int j = 0; j < 4; ++j) {
          const bf16x8 bv = *(const bf16x8*)&L.a.rzf[(size_t)((j * 20 + ks) * 64 + lane) * 8];
          acc[j] = mfma16(av, bv, acc[j]);
        }
        #pragma unroll
        for (int j = 0; j < 2; ++j) {
          const bf16x8 bv = *(const bf16x8*)&L.a.nif[(size_t)((j * 4 + ks) * 64 + lane) * 8];
          acci[j] = mfma16(av, bv, acci[j]);
        }
      }
      // h part: ks 0..15 feeds rzf (h-frags) and nhf; coherent 8B loads
      #pragma unroll 4
      for (int ks = 0; ks < 16; ++ks) {
        const int ko = ks * 32 + q8;
        u64 hq[2];
        hq[0] = __hip_atomic_load((u64*)(pah + ko),     __ATOMIC_RELAXED, __HIP_MEMORY_SCOPE_AGENT);
        hq[1] = __hip_atomic_load((u64*)(pah + ko) + 1, __ATOMIC_RELAXED, __HIP_MEMORY_SCOPE_AGENT);
        const bf16x8 av = *(const bf16x8*)hq;
        #pragma unroll
        for (int j = 0; j < 4; ++j) {
          const bf16x8 bv = *(const bf16x8*)&L.a.rzf[(size_t)((j * 20 + 4 + ks) * 64 + lane) * 8];
          acc[j] = mfma16(av, bv, acc[j]);
        }
        #pragma unroll
        for (int j = 0; j < 2; ++j) {
          const bf16x8 bv = *(const bf16x8*)&L.a.nhf[(size_t)((j * 16 + ks) * 64 + lane) * 8];
          accn[j] = mfma16(av, bv, accn[j]);
        }
      }
      // dump gate sums to LDS exchange (C/D: col=lane&15, row=q*4+reg)
      #pragma unroll
      for (int j = 0; j < 4; ++j) {
        const int sl = j >> 1, cb = (j & 1) * 16 + col16;
        #pragma unroll
        for (int rg = 0; rg < 4; ++rg)
          L.a.ex[sl][wv * 16 + q * 4 + rg][cb] = acc[j][rg];
      }
      #pragma unroll
      for (int j = 0; j < 2; ++j) {
        const int cb = j * 16 + col16;
        #pragma unroll
        for (int rg = 0; rg < 4; ++rg) {
          L.a.ex[2][wv * 16 + q * 4 + rg][cb] = accn[j][rg];
          L.a.ex[3][wv * 16 + q * 4 + rg][cb] = acci[j][rg];
        }
      }
      __syncthreads();
      // elementwise GRU update, 4 cols/thread, 8B coherent I/O
      for (int e = tid; e < 512; e += NTHR) {
        const int row = e >> 3, cq = (e & 7) << 2;
        const int bidx = b0 + row;
        u64 hp8 = __hip_atomic_load((u64*)(hr + (size_t)bidx * HDIM + c0 + cq),
                                    __ATOMIC_RELAXED, __HIP_MEMORY_SCOPE_AGENT);
        const bf16_t* hp4 = (const bf16_t*)&hp8;
        bf16_t hw4[4], fw4[4];
        const bool v = (t < seqA[row]);
        #pragma unroll
        for (int j = 0; j < 4; ++j) {
          const int c = cq + j;
          const float gr  = L.a.ex[0][row][c] + biasA[0][c];
          const float gz  = L.a.ex[1][row][c] + biasA[1][c];
          const float gnh = L.a.ex[2][row][c] + biasA[3][c];
          const float gni = L.a.ex[3][row][c] + biasA[2][c];
          const float r = sigm(gr), zg = sigm(gz);
          const float n = tanh_f(gni + r * gnh);
          const float hp = (float)hp4[j];
          const float hnew = (1.f - zg) * n + zg * hp;
          hw4[j] = (bf16_t)(v ? hnew : hp);
          fw4[j] = (bf16_t)(v ? hnew : 0.f);
        }
        __hip_atomic_store((u64*)(hw + (size_t)bidx * HDIM + c0 + cq), *(u64*)hw4,
                           __ATOMIC_RELAXED, __HIP_MEMORY_SCOPE_AGENT);
        __hip_atomic_store((u64*)(fw + (size_t)bidx * HDIM + c0 + cq), *(u64*)fw4,
                           __ATOMIC_RELAXED, __HIP_MEMORY_SCOPE_AGENT);
      }
      __syncthreads();                       // drain h/ff stores
      if (tid == 0) atomicAdd(barA, 1u);     // release: h[t], ff[t] visible
    }
  } else {
    const int cidx = blk - 128;
    const int fc = cidx >> 3;      // 0..15
    const int oc = fc & 3;         // out-col group (4 x 16 cols)
    const int kq = fc >> 2;        // K-quarter (4 x 256)
    const bool isFin = (fc < 4);   // finalizer blocks (one per (g, oc))
    b0 = (cidx & 7) * 64;          // batch group (same XCD residue as A)
    f0 = fc * 64;                  // FF col group (16)
    const int o0 = oc * 16;
    for (int i = tid; i < 64 * 64; i += NTHR) {   // w1f: fi=j*16+ks
      const int ln = i & 63, fi = i >> 6;
      const int j = fi >> 4, ks = fi & 15;
      const int cc = ln & 15, qq = ln >> 4;
      const int fcol = f0 + j * 16 + cc;
      const int kb = ks * 32 + qq * 8;
      bf16_t* dst = &L.b.w1f[(size_t)i * 8];
      for (int e = 0; e < 8; ++e) dst[e] = (bf16_t)W1[(size_t)(kb + e) * FFD + fcol];
    }
    if (tid < 64) b1s[tid] = b1[f0 + tid];
    for (int i = tid; i < 8 * 64; i += NTHR) {    // w2f: own K-quarter, fi=ks<8
      const int ln = i & 63, ks = i >> 6;
      const int cc = ln & 15, qq = ln >> 4;
      const int kb = kq * 256 + ks * 32 + qq * 8;
      bf16_t* dst = &L.b.w2f[(size_t)i * 8];
      for (int e = 0; e < 8; ++e) dst[e] = (bf16_t)W2[(kb + e) * OUTD + o0 + cc];
    }
    if (isFin) {
      if (tid < 16) b2s[tid] = b2[o0 + tid];
      if (tid < 64) seqC[tid] = seq[b0 + tid];
    }
    __syncthreads();               // LDS staging visible block-wide

    // ---- B loop: iter u = FF1(t=u), FF2-chunk adds(t=u-1), finalize(t=u-2)
    float* pg = psc + (size_t)grp * PGRP + (size_t)oc * (64 * 16);
    for (int u = 0; u <= TT + 1; ++u) {
      if (tid == 0) {
        wait_ge(barB, 16u * (unsigned)u);                    // siblings done u-1
        if (u < TT) wait_ge(barA, 16u * (unsigned)(u + 2));  // ff[u] visible
      }
      __syncthreads();

      if (u < TT) {                        // FF1 for t = u
        const int t = u;
        bf16_t* fr = ff + (size_t)(t & 1) * BB * HDIM;
        bf16_t* hwid = hd + (size_t)(t & 1) * BB * FFD;
        const int rB = b0 + wv * 16 + col16;
        bf16_t* pa = fr + (size_t)rB * HDIM;
        const f32x4 zz = {0.f, 0.f, 0.f, 0.f};
        f32x4 acc[4] = {zz, zz, zz, zz};
        #pragma unroll 4
        for (int ks = 0; ks < 16; ++ks) {
          const int ko = ks * 32 + q8;
          u64 fq[2];
          fq[0] = __hip_atomic_load((u64*)(pa + ko),     __ATOMIC_RELAXED, __HIP_MEMORY_SCOPE_AGENT);
          fq[1] = __hip_atomic_load((u64*)(pa + ko) + 1, __ATOMIC_RELAXED, __HIP_MEMORY_SCOPE_AGENT);
          const bf16x8 av = *(const bf16x8*)fq;
          #pragma unroll
          for (int j = 0; j < 4; ++j) {
            const bf16x8 bv = *(const bf16x8*)&L.b.w1f[(size_t)((j * 16 + ks) * 64 + lane) * 8];
            acc[j] = mfma16(av, bv, acc[j]);
          }
        }
        // relu + bias -> LDS restage -> contiguous 8B coherent stores
        #pragma unroll
        for (int j = 0; j < 4; ++j) {
          const int fcc = j * 16 + col16;
          #pragma unroll
          for (int rg = 0; rg < 4; ++rg)
            L.b.st[(wv * 16 + q * 4 + rg) * 72 + fcc] =
                (bf16_t)fmaxf(acc[j][rg] + b1s[fcc], 0.f);
        }
        __syncthreads();
        for (int w = tid; w < 1024; w += NTHR) {
          const int r = w >> 4, cq = (w & 15) * 4;
          const u64 pk = *(const u64*)&L.b.st[r * 72 + cq];
          __hip_atomic_store((u64*)(hwid + (size_t)(b0 + r) * FFD + f0 + cq), pk,
                             __ATOMIC_RELAXED, __HIP_MEMORY_SCOPE_AGENT);
        }
      }
      if (u >= 1 && u <= TT) {             // FF2 chunk for t = u-1: 8 trips
        const int t = u - 1;
        bf16_t* hr2 = hd + (size_t)(t & 1) * BB * FFD;
        const int rC = b0 + wv * 16 + col16;
        bf16_t* pa = hr2 + (size_t)rC * FFD;
        f32x4 acc = {0.f, 0.f, 0.f, 0.f};
        #pragma unroll 4
        for (int ks = 0; ks < 8; ++ks) {
          const int ko = kq * 256 + ks * 32 + q8;
          u64 hq[2];
          hq[0] = __hip_atomic_load((u64*)(pa + ko),     __ATOMIC_RELAXED, __HIP_MEMORY_SCOPE_AGENT);
          hq[1] = __hip_atomic_load((u64*)(pa + ko) + 1, __ATOMIC_RELAXED, __HIP_MEMORY_SCOPE_AGENT);
          const bf16x8 av = *(const bf16x8*)hq;
          const bf16x8 bv = *(const bf16x8*)&L.b.w2f[(size_t)(ks * 64 + lane) * 8];
          acc = mfma16(av, bv, acc);
        }
        float* pb = pg + (size_t)(t & 1) * PSLOT;
        #pragma unroll
        for (int rg = 0; rg < 4; ++rg)
          atomicAdd(pb + (wv * 16 + q * 4 + rg) * 16 + col16, acc[rg]);
      }
      if (isFin && u >= 2) {               // finalize t = u-2 from pscr
        const int t2 = u - 2;
        float* pb = pg + (size_t)(t2 & 1) * PSLOT;
        const int row = tid >> 2, c4 = (tid & 3) * 4;
        float* pp = pb + row * 16 + c4;
        u64 p0 = __hip_atomic_load((u64*)pp,     __ATOMIC_RELAXED, __HIP_MEMORY_SCOPE_AGENT);
        u64 p1 = __hip_atomic_load((u64*)pp + 1, __ATOMIC_RELAXED, __HIP_MEMORY_SCOPE_AGENT);
        float pv[4];
        ((u64*)pv)[0] = p0;
        ((u64*)pv)[1] = p1;
        const bool v = (t2 < seqC[row]);
        float* po = out + ((size_t)(b0 + row) * TT + t2) * OUTD + o0 + c4;
        #pragma unroll
        for (int j = 0; j < 4; ++j)
          po[j] = v ? (pv[j] + b2s[c4 + j]) : PADV;
        // re-zero the slot for t = u (replay-safe, gated by barB >= 16(u+2))
        __hip_atomic_store((u64*)pp,     0ull, __ATOMIC_RELAXED, __HIP_MEMORY_SCOPE_AGENT);
        __hip_atomic_store((u64*)pp + 1, 0ull, __ATOMIC_RELAXED, __HIP_MEMORY_SCOPE_AGENT);
      }
      __syncthreads();                     // drain hd stores / adds / zeros
      if (tid == 0) atomicAdd(barB, 1u);   // iter u complete
    }
  }
}

extern "C" void kernel_launch(void* const* d_in, const int* in_sizes, int n_in,
                              void* d_out, int out_size, void* d_ws, size_t ws_size,
                              hipStream_t stream) {
  const float* x   = (const float*)d_in[0];
  const int*   seq = (const int*)d_in[1];
  const float* Wih = (const float*)d_in[2];
  const float* Whh = (const float*)d_in[3];
  const float* bih = (const float*)d_in[4];
  const float* bhh = (const float*)d_in[5];
  const float* W1  = (const float*)d_in[6];
  const float* b1  = (const float*)d_in[7];
  const float* W2  = (const float*)d_in[8];
  const float* b2  = (const float*)d_in[9];
  float* out = (float*)d_out;
  char* ws = (char*)d_ws;

  unsigned* bar = (unsigned*)ws;                       // 16 counters, 128B apart
  float* psc = (float*)(ws + 4096);                    // 2*PSLOT f32 = 256KB
  bf16_t* hb = (bf16_t*)(ws + 4096 + 2 * PSLOT * 4);   // h ping-pong  2*B*H
  bf16_t* ff = hb + (size_t)2 * BB * HDIM;             // ffin ping-pong
  bf16_t* hd = ff + (size_t)2 * BB * HDIM;             // hid ping-pong 2*B*FF
  // total scratch ~4.5 MB

  hipMemsetAsync(ws, 0, 4096 + 2 * PSLOT * 4, stream);
  void* args[] = {&x, &seq, &Wih, &Whh, &bih, &bhh, &W1, &b1, &W2, &b2,
                  &out, &hb, &ff, &hd, &psc, &bar};
  hipLaunchCooperativeKernel((void*)gru_net_kernel, dim3(NBLK), dim3(NTHR),
                             args, 0, stream);
}